// Round 4
// baseline (237.209 us; speedup 1.0000x reference)
//
#include <hip/hip_runtime.h>
#include <math.h>

#define ROW_LEN 4096
#define NROWS   8192
#define BLOCK   256
#define WAVES_PER_BLOCK (BLOCK / 64)
// 4096 floats / 64 lanes = 64 floats/lane = 16 float4/lane
#define F4_PER_LANE 16

// native clang vector type — accepted by __builtin_nontemporal_store
typedef float vf4 __attribute__((ext_vector_type(4)));

__global__ __launch_bounds__(BLOCK) void masked_softmax_wave(
    const float* __restrict__ X,
    const int* __restrict__ N,
    float* __restrict__ out)
{
    const int wave = threadIdx.x >> 6;
    const int lane = threadIdx.x & 63;
    const int row  = blockIdx.x * WAVES_PER_BLOCK + wave;

    // n is wave-uniform (one row per wave) — force it scalar
    const int n = __builtin_amdgcn_readfirstlane(N[row]);

    const vf4* __restrict__ Xr = (const vf4*)(X + (size_t)row * ROW_LEN);
    vf4* __restrict__ Or       = (vf4*)(out + (size_t)row * ROW_LEN);

    // ---- load entire row into registers (coalesced float4, REGULAR loads:
    // NT-load hint suspected of capping read BW by bypassing L2) ----
    vf4 v[F4_PER_LANE];
    #pragma unroll
    for (int j = 0; j < F4_PER_LANE; j++) {
        v[j] = Xr[lane + 64 * j];
    }

    // ---- masked max over registers ----
    float m = -INFINITY;
    #pragma unroll
    for (int j = 0; j < F4_PER_LANE; j++) {
        const int col = 4 * (lane + 64 * j);
        m = fmaxf(m, (col + 0 < n) ? v[j].x : -INFINITY);
        m = fmaxf(m, (col + 1 < n) ? v[j].y : -INFINITY);
        m = fmaxf(m, (col + 2 < n) ? v[j].z : -INFINITY);
        m = fmaxf(m, (col + 3 < n) ? v[j].w : -INFINITY);
    }
    // wave-wide max, butterfly (no LDS, no barrier)
    #pragma unroll
    for (int off = 1; off < 64; off <<= 1)
        m = fmaxf(m, __shfl_xor(m, off, 64));

    // ---- exp, mask folded in (v[] becomes masked exp), masked sum ----
    float s = 0.0f;
    #pragma unroll
    for (int j = 0; j < F4_PER_LANE; j++) {
        const int col = 4 * (lane + 64 * j);
        float ex = __expf(v[j].x - m);
        float ey = __expf(v[j].y - m);
        float ez = __expf(v[j].z - m);
        float ew = __expf(v[j].w - m);
        ex = (col + 0 < n) ? ex : 0.0f;
        ey = (col + 1 < n) ? ey : 0.0f;
        ez = (col + 2 < n) ? ez : 0.0f;
        ew = (col + 3 < n) ? ew : 0.0f;
        v[j].x = ex; v[j].y = ey; v[j].z = ez; v[j].w = ew;
        s += (ex + ey) + (ez + ew);
    }
    // wave-wide sum, butterfly
    #pragma unroll
    for (int off = 1; off < 64; off <<= 1)
        s += __shfl_xor(s, off, 64);

    const float inv = 1.0f / s;

    // ---- store: pure multiply, nontemporal (streaming write) ----
    #pragma unroll
    for (int j = 0; j < F4_PER_LANE; j++) {
        vf4 o;
        o.x = v[j].x * inv;
        o.y = v[j].y * inv;
        o.z = v[j].z * inv;
        o.w = v[j].w * inv;
        __builtin_nontemporal_store(o, &Or[lane + 64 * j]);
    }
}

extern "C" void kernel_launch(void* const* d_in, const int* in_sizes, int n_in,
                              void* d_out, int out_size, void* d_ws, size_t ws_size,
                              hipStream_t stream) {
    const float* X = (const float*)d_in[0];
    const int*   N = (const int*)d_in[1];
    float* out = (float*)d_out;
    masked_softmax_wave<<<NROWS / WAVES_PER_BLOCK, BLOCK, 0, stream>>>(X, N, out);
}